// Round 2
// baseline (118.264 us; speedup 1.0000x reference)
//
#include <hip/hip_runtime.h>

// Fused CNN, conv1 AND conv2 via bf16 MFMA (16x16x32).
// R5: stage-1 conv1 moved to the (87% idle) matrix pipe. Per conv row r:
//     build im2col strip icb[48 m][40 k-pad] bf16 in LDS with pooled-window-major
//     rows (m-slot -> conv x = 2*(m>>2) + (m&3)), K=32 with taps 0..8 live (w-frag
//     zero for k>=9). D layout row=(lane>>4)*4+reg puts a pool window's 3 conv
//     values IN-LANE -> x-pool = max3, y-pool = 3-row register ring. Bias rides in
//     the MFMA C operand. Stage-1 VALU ~2400 -> ~700 ops/thread, VGPR stays <=64
//     (R4 lesson: 80 VGPR crosses the 64-reg wave-slot cliff, 5->4 blocks/CU).
//     icb zero-initialized once: 0 x NaN = NaN in MFMA, uninit LDS is dangerous.
//     Keeps R4's bank fixes: cbuf stride 101 (was 8-way), h2t stride 65.

typedef __attribute__((ext_vector_type(8))) short short8;   // 8 x bf16 (4 VGPRs)
typedef __attribute__((ext_vector_type(4))) float f32x4;

__device__ inline short f2bf(float f) {   // fp32 -> bf16, round-to-nearest-even
    union { float f; unsigned u; } v; v.f = f;
    unsigned r = (v.u + 0x7FFFu + ((v.u >> 16) & 1u)) >> 16;
    return (short)r;
}

// w2r[s][cout][cin] (bf16), s = ky*3+kx: MFMA A-fragments contiguous in cin.
__global__ __launch_bounds__(256) void prep_w2(const float* __restrict__ w2,
                                               short* __restrict__ w2r) {
    int i = blockIdx.x * 256 + threadIdx.x;      // 9*64*64 = 36864
    if (i >= 36864) return;
    int s = i >> 12, cout = (i >> 6) & 63, cin = i & 63;
    w2r[i] = f2bf(w2[cout * 576 + cin * 9 + s]);
}

__global__ __launch_bounds__(256) void convnet_fused(
    const float* __restrict__ x,   // [B,1,28,28]
    const float* __restrict__ w1,  // [64,1,3,3]
    const float* __restrict__ b1,  // [64]
    const short* __restrict__ w2r, // [9][64][64] bf16 (prep)
    const float* __restrict__ b2,  // [64]
    const float* __restrict__ w3,  // [10,64,4,4]
    const float* __restrict__ b3,  // [10]
    float* __restrict__ out)       // [B,10]
{
    // Overlay plan (floats):
    //   [0..5184)     h1t bf16 [144 pos][72 cin-stride]
    //   [5184..5576)  imgbf bf16 [784]
    //   [5576..7496)  icb bf16 [2][48][40]  (im2col double buffer)
    //   stage2+: cbuf fp32 [64][101] at [0..6464) (h1t/imgbf/icb dead)
    //   [6464..7504)  h2t fp32 [16 pos][65 stride]
    //   [0..160)      stage-3 partials
    __shared__ float lds_f[7504];                // 30016 B -> 5 blocks/CU
    short* h1t   = (short*)lds_f;
    short* imgbf = (short*)(lds_f + 5184);
    short* icb   = (short*)(lds_f + 5576);       // [2][48][40] shorts
    float* cbuf  = lds_f;                        // conv2buf fp32 [64][101]
    float* h2t   = lds_f + 6464;
    float* prt   = lds_f;

    const int n_img = blockIdx.x;
    const int t = threadIdx.x;
    const int wv = t >> 6, lane = t & 63;
    const int g16 = lane >> 4, mcol = lane & 15;

    // ---- zero icb pad region once (k>=9 lanes feed MFMA; 0*NaN=NaN hazard) ----
    for (int i = t; i < 3840; i += 256) icb[i] = 0;

    // ---- load input image -> bf16 ----
    const float* img_g = x + (size_t)n_img * 784;
    for (int i = t; i < 784; i += 256) imgbf[i] = f2bf(img_g[i]);

    // ---- stage-1 constants: w1 B-fragment (col=cout, k=g16*8+i), bias as C ----
    const int cout1 = wv * 16 + mcol;            // this lane's conv1 channel
    short8 wfrag;
    #pragma unroll
    for (int i = 0; i < 8; ++i) {
        const int k = g16 * 8 + i;
        wfrag[i] = (k < 9) ? f2bf(w1[cout1 * 9 + k]) : (short)0;
    }
    const float bias1 = b1[cout1];
    const f32x4 biasv = {bias1, bias1, bias1, bias1};

    // ---- im2col build precompute: entries e0=t, e1=256+t (t<176); 48*9=432 ----
    // m-slot -> conv x = 2*(m>>2) + (m&3); entry value = imgbf[(r+ky)*28 + x + kx]
    const int m0 = t / 9, k0 = t - m0 * 9;
    const int src0 = (k0 / 3) * 28 + 2 * (m0 >> 2) + (m0 & 3) + (k0 % 3);
    const int dst0 = m0 * 40 + k0;
    const int e1 = 256 + t;
    const int m1 = e1 / 9, k1 = e1 - m1 * 9;
    const int src1 = (k1 / 3) * 28 + 2 * (m1 >> 2) + (m1 & 3) + (k1 % 3);
    const int dst1 = m1 * 40 + k1;
    const bool has1 = (t < 176);

    __syncthreads();

    // ---- stage 1: conv1 via MFMA + in-register 3x3 s2 pool + relu -> h1t ----
    // conv rows 0..24 (row 25 / col 25 never enter a pool window)
    {
        float ring[3][3];                        // [row%3][mtile] colmax
        #pragma unroll
        for (int r = 0; r < 25; ++r) {
            const int buf = (r & 1) * 1920;
            icb[buf + dst0] = imgbf[src0 + 28 * r];
            if (has1) icb[buf + dst1] = imgbf[src1 + 28 * r];
            __syncthreads();                     // build(r) done; dbl-buf covers prev reads
            #pragma unroll
            for (int mt = 0; mt < 3; ++mt) {
                const short8 a = *(const short8*)(icb + buf + (mt * 16 + mcol) * 40 + g16 * 8);
                const f32x4 d = __builtin_amdgcn_mfma_f32_16x16x32_bf16(a, wfrag, biasv, 0, 0, 0);
                ring[r % 3][mt] = fmaxf(fmaxf(d[0], d[1]), d[2]);   // x-pool (in-lane window)
            }
            if (r >= 2 && (r & 1) == 0) {        // pooled row py complete
                const int py = r / 2 - 1;
                #pragma unroll
                for (int mt = 0; mt < 3; ++mt) {
                    const int px = mt * 4 + g16;
                    const float v = fmaxf(fmaxf(ring[0][mt], ring[1][mt]), ring[2][mt]);
                    h1t[(py * 12 + px) * 72 + cout1] = f2bf(fmaxf(v, 0.0f));
                }
            }
        }
    }
    __syncthreads();

    // ---- stage 2: conv2 as MFMA GEMM (M=64 cout, N=100 pad 112, K=576) ----
    const int quad = g16, mrow = mcol;
    {
        int base_el[7];
        #pragma unroll
        for (int nt = 0; nt < 7; ++nt) {
            int n = nt * 16 + mrow; if (n > 99) n = 99;   // clamp pad cols (discarded)
            int y = n / 10, xx = n - y * 10;
            base_el[nt] = (y * 12 + xx) * 72;
        }
        f32x4 acc[7];
        #pragma unroll
        for (int nt = 0; nt < 7; ++nt) acc[nt] = (f32x4){0.f, 0.f, 0.f, 0.f};

        #pragma unroll
        for (int ks = 0; ks < 18; ++ks) {
            const int s = ks >> 1, h = ks & 1;
            const int ky = s / 3, kx = s - ky * 3;
            const short8 a = *(const short8*)(w2r + s * 4096 + (wv * 16 + mrow) * 64
                                              + h * 32 + quad * 8);
            #pragma unroll
            for (int nt = 0; nt < 7; ++nt) {
                const short8 b = *(const short8*)(h1t + base_el[nt]
                                                  + (ky * 12 + kx) * 72 + h * 32 + quad * 8);
                acc[nt] = __builtin_amdgcn_mfma_f32_16x16x32_bf16(a, b, acc[nt], 0, 0, 0);
            }
        }
        __syncthreads();   // all h1t reads done; overlay region reusable
        // epilogue: D[row=quad*4+r][col=mrow] -> cbuf[cout][pos] + bias
        #pragma unroll
        for (int nt = 0; nt < 7; ++nt) {
            const int n = nt * 16 + mrow;
            if (n < 100) {
                #pragma unroll
                for (int r = 0; r < 4; ++r) {
                    const int cout = wv * 16 + quad * 4 + r;
                    cbuf[cout * 101 + n] = acc[nt][r] + b2[cout];
                }
            }
        }
    }
    __syncthreads();

    // ---- stage 2b: pool 3x3 s2 + relu -> h2t[pos*65+cin] fp32 ----
    {
        const int c = t >> 2, q = t & 3;
        const float* cb = cbuf + c * 101;
        #pragma unroll
        for (int k = 0; k < 4; ++k) {
            const int pos = q * 4 + k;
            const int py = pos >> 2, px = pos & 3;
            float m = -1e30f;
            #pragma unroll
            for (int a = 0; a < 3; ++a)
                #pragma unroll
                for (int b = 0; b < 3; ++b)
                    m = fmaxf(m, cb[(2 * py + a) * 10 + (2 * px + b)]);
            h2t[pos * 65 + c] = fmaxf(m, 0.0f);
        }
    }
    __syncthreads();

    // ---- stage 3: conv3 4x4 -> out[n][10] ----
    if (t < 160) {
        const int o = t >> 4, l = t & 15;
        const float* w3o = w3 + o * 1024;
        float s = 0.0f;
        #pragma unroll
        for (int cc = 0; cc < 4; ++cc) {
            const int cin = l * 4 + cc;
            const float4 wv4a = *(const float4*)(w3o + cin * 16);
            const float4 wv4b = *(const float4*)(w3o + cin * 16 + 4);
            const float4 wv4c = *(const float4*)(w3o + cin * 16 + 8);
            const float4 wv4d = *(const float4*)(w3o + cin * 16 + 12);
            const float* hh = h2t + cin;           // h2t[k*65+cin]
            s += hh[0*65] * wv4a.x + hh[1*65] * wv4a.y + hh[2*65] * wv4a.z + hh[3*65] * wv4a.w;
            s += hh[4*65] * wv4b.x + hh[5*65] * wv4b.y + hh[6*65] * wv4b.z + hh[7*65] * wv4b.w;
            s += hh[8*65] * wv4c.x + hh[9*65] * wv4c.y + hh[10*65] * wv4c.z + hh[11*65] * wv4c.w;
            s += hh[12*65] * wv4d.x + hh[13*65] * wv4d.y + hh[14*65] * wv4d.z + hh[15*65] * wv4d.w;
        }
        prt[t] = s;   // cbuf dead (pool reads barriered above)
    }
    __syncthreads();
    if (t < 10) {
        float s = b3[t];
        #pragma unroll
        for (int l = 0; l < 16; ++l) s += prt[t * 16 + l];
        out[(size_t)n_img * 10 + t] = s;
    }
}

extern "C" void kernel_launch(void* const* d_in, const int* in_sizes, int n_in,
                              void* d_out, int out_size, void* d_ws, size_t ws_size,
                              hipStream_t stream) {
    const float* x  = (const float*)d_in[0];
    const float* w1 = (const float*)d_in[1];
    const float* b1 = (const float*)d_in[2];
    const float* w2 = (const float*)d_in[3];
    const float* b2 = (const float*)d_in[4];
    const float* w3 = (const float*)d_in[5];
    const float* b3 = (const float*)d_in[6];
    float* out = (float*)d_out;
    short* w2r = (short*)d_ws;            // 36864 bf16 = 73728 B

    const int B = in_sizes[0] / 784;      // 2048
    prep_w2<<<144, 256, 0, stream>>>(w2, w2r);
    convnet_fused<<<B, 256, 0, stream>>>(x, w1, b1, w2r, b2, w3, b3, out);
}

// Round 3
// 115.212 us; speedup vs baseline: 1.0265x; 1.0265x over previous
//
#include <hip/hip_runtime.h>

// Fused CNN, conv2 via bf16 MFMA (16x16x32).
// R6: R3 structure (proven 52us, 64 VGPR) + LDS diet for occupancy.
//     Theory: R3 is latency-bound (VALU 55 / Mfma 12.5 / occ 34 - nothing
//     saturated); 5 blocks/CU gives only 5 waves/SIMD. cbuf fp32->bf16 halves
//     the stage-2 overlay; peak LDS = h1t(20736) + img(3136) = 23872 B ->
//     6 blocks/CU (+20% resident waves). VGPR must stay <=64 (R4 lesson:
//     65..128 VGPR -> 4 waves/SIMD cliff). Keeps R4 bank fixes (cbuf stride
//     101: stride 100 was an 8-way conflict; h2t stride 65).
//     R5 lesson folded in: no per-row barriers, no redundant cross-wave
//     strip reads - stage-1 scalar's img reads are wave-broadcast (16
//     same-quadrant lanes share one address) so they are cheap on LDS pipe.

typedef __attribute__((ext_vector_type(8))) short short8;   // 8 x bf16 (4 VGPRs)
typedef __attribute__((ext_vector_type(4))) float f32x4;

__device__ inline short f2bf(float f) {   // fp32 -> bf16, round-to-nearest-even
    union { float f; unsigned u; } v; v.f = f;
    unsigned r = (v.u + 0x7FFFu + ((v.u >> 16) & 1u)) >> 16;
    return (short)r;
}
__device__ inline float bf2f(short s) {
    union { unsigned u; float f; } v; v.u = ((unsigned)(unsigned short)s) << 16;
    return v.f;
}

// w2r[s][cout][cin] (bf16), s = ky*3+kx: MFMA A-fragments contiguous in cin.
__global__ __launch_bounds__(256) void prep_w2(const float* __restrict__ w2,
                                               short* __restrict__ w2r) {
    int i = blockIdx.x * 256 + threadIdx.x;      // 9*64*64 = 36864
    if (i >= 36864) return;
    int s = i >> 12, cout = (i >> 6) & 63, cin = i & 63;
    w2r[i] = f2bf(w2[cout * 576 + cin * 9 + s]);
}

__global__ __launch_bounds__(256) void convnet_fused(
    const float* __restrict__ x,   // [B,1,28,28]
    const float* __restrict__ w1,  // [64,1,3,3]
    const float* __restrict__ b1,  // [64]
    const short* __restrict__ w2r, // [9][64][64] bf16 (prep)
    const float* __restrict__ b2,  // [64]
    const float* __restrict__ w3,  // [10,64,4,4]
    const float* __restrict__ b3,  // [10]
    float* __restrict__ out)       // [B,10]
{
    // Overlay plan (bytes):
    //   [0..20736)     h1t bf16 [144 pos][72 cin-stride]
    //   [20736..23872) img fp32 28x28
    //   stage2+ (h1t dead after mid-stage-2 barrier):
    //   [0..12928)     cbuf bf16 [64][101]
    //   [12928..17088) h2t fp32 [16 pos][65 stride]
    //   [0..640)       stage-3 partials (cbuf dead by then)
    __shared__ float lds_f[5968];                // 23872 B -> 6 blocks/CU
    short* h1t   = (short*)lds_f;
    float* img   = lds_f + 5184;
    short* cbuf  = (short*)lds_f;                // bf16 [64][101]
    float* h2t   = lds_f + 3232;
    float* prt   = lds_f;

    const int n_img = blockIdx.x;
    const int t = threadIdx.x;
    const int c = t >> 2;        // 0..63
    const int q = t & 3;         // quadrant

    // ---- load input image ----
    const float* img_g = x + (size_t)n_img * 784;
    for (int i = t; i < 784; i += 256) img[i] = img_g[i];
    __syncthreads();

    // ---- stage 1: conv1 + pool 3x3 s2 + relu -> h1t[pos][c] (bf16), no recompute ----
    {
        const int oy = (q >> 1) * 6, ox = (q & 1) * 6;   // pooled quadrant origin
        const int iy0 = 2 * oy, ix0 = 2 * ox;            // input/conv region origin
        float w[9];
        #pragma unroll
        for (int k = 0; k < 9; ++k) w[k] = w1[c * 9 + k];
        const float bias = b1[c];

        float in0[15], in1[15], in2[15];                 // ring of 3 input rows
        #pragma unroll
        for (int s = 0; s < 15; ++s) in0[s] = img[(iy0 + 0) * 28 + ix0 + s];
        #pragma unroll
        for (int s = 0; s < 15; ++s) in1[s] = img[(iy0 + 1) * 28 + ix0 + s];
        float cm[3][6];                                  // colmax ring (3 conv rows)

        #pragma unroll
        for (int r = 0; r < 13; ++r) {                   // conv rows, computed once
            #pragma unroll
            for (int s = 0; s < 15; ++s) in2[s] = img[(iy0 + r + 2) * 28 + ix0 + s];
            #pragma unroll
            for (int px = 0; px < 6; ++px) cm[r % 3][px] = -1e30f;
            #pragma unroll
            for (int xx = 0; xx < 13; ++xx) {
                float a = bias;
                #pragma unroll
                for (int j = 0; j < 3; ++j) {
                    a += in0[xx + j] * w[j];
                    a += in1[xx + j] * w[3 + j];
                    a += in2[xx + j] * w[6 + j];
                }
                // fold conv value into colmax: px with 2px <= xx <= 2px+2
                if ((xx & 1) == 0) {
                    if (xx >= 2 && xx <= 12) cm[r % 3][xx / 2 - 1] = fmaxf(cm[r % 3][xx / 2 - 1], a);
                    if (xx <= 10)            cm[r % 3][xx / 2]     = fmaxf(cm[r % 3][xx / 2], a);
                } else {
                    cm[r % 3][xx / 2] = fmaxf(cm[r % 3][xx / 2], a);
                }
            }
            if (r >= 2 && (r & 1) == 0) {                // pooled row py = r/2 - 1 complete
                const int py = r / 2 - 1;
                #pragma unroll
                for (int px = 0; px < 6; ++px) {
                    float m = fmaxf(fmaxf(cm[0][px], cm[1][px]), cm[2][px]);
                    h1t[((oy + py) * 12 + ox + px) * 72 + c] = f2bf(fmaxf(m, 0.0f));
                }
            }
            #pragma unroll
            for (int s = 0; s < 15; ++s) { in0[s] = in1[s]; in1[s] = in2[s]; }
        }
    }
    __syncthreads();

    // ---- stage 2: conv2 as MFMA GEMM (M=64 cout, N=100 pad 112, K=576) ----
    const int wv = t >> 6, lane = t & 63;
    const int quad = lane >> 4, mrow = lane & 15;
    {
        int base_el[7];
        #pragma unroll
        for (int nt = 0; nt < 7; ++nt) {
            int n = nt * 16 + mrow; if (n > 99) n = 99;   // clamp pad cols (discarded)
            int y = n / 10, xx = n - y * 10;
            base_el[nt] = (y * 12 + xx) * 72;
        }
        f32x4 acc[7];
        #pragma unroll
        for (int nt = 0; nt < 7; ++nt) acc[nt] = (f32x4){0.f, 0.f, 0.f, 0.f};

        #pragma unroll
        for (int ks = 0; ks < 18; ++ks) {
            const int s = ks >> 1, h = ks & 1;
            const int ky = s / 3, kx = s - ky * 3;
            const short8 a = *(const short8*)(w2r + s * 4096 + (wv * 16 + mrow) * 64
                                              + h * 32 + quad * 8);
            #pragma unroll
            for (int nt = 0; nt < 7; ++nt) {
                const short8 b = *(const short8*)(h1t + base_el[nt]
                                                  + (ky * 12 + kx) * 72 + h * 32 + quad * 8);
                acc[nt] = __builtin_amdgcn_mfma_f32_16x16x32_bf16(a, b, acc[nt], 0, 0, 0);
            }
        }
        __syncthreads();   // all h1t + img reads done; overlay region reusable
        // epilogue: D[row=quad*4+r][col=mrow] -> cbuf[cout][pos] bf16, + bias
        #pragma unroll
        for (int nt = 0; nt < 7; ++nt) {
            const int n = nt * 16 + mrow;
            if (n < 100) {
                #pragma unroll
                for (int r = 0; r < 4; ++r) {
                    const int cout = wv * 16 + quad * 4 + r;
                    cbuf[cout * 101 + n] = f2bf(acc[nt][r] + b2[cout]);
                }
            }
        }
    }
    __syncthreads();

    // ---- stage 2b: pool 3x3 s2 + relu -> h2t[pos*65+cin] fp32 ----
    {
        const short* cb = cbuf + c * 101;
        #pragma unroll
        for (int k = 0; k < 4; ++k) {
            const int pos = q * 4 + k;
            const int py = pos >> 2, px = pos & 3;
            float m = -1e30f;
            #pragma unroll
            for (int a = 0; a < 3; ++a)
                #pragma unroll
                for (int b = 0; b < 3; ++b)
                    m = fmaxf(m, bf2f(cb[(2 * py + a) * 10 + (2 * px + b)]));
            h2t[pos * 65 + c] = fmaxf(m, 0.0f);
        }
    }
    __syncthreads();

    // ---- stage 3: conv3 4x4 -> out[n][10] ----
    if (t < 160) {
        const int o = t >> 4, l = t & 15;
        const float* w3o = w3 + o * 1024;
        float s = 0.0f;
        #pragma unroll
        for (int cc = 0; cc < 4; ++cc) {
            const int cin = l * 4 + cc;
            const float4 wv4a = *(const float4*)(w3o + cin * 16);
            const float4 wv4b = *(const float4*)(w3o + cin * 16 + 4);
            const float4 wv4c = *(const float4*)(w3o + cin * 16 + 8);
            const float4 wv4d = *(const float4*)(w3o + cin * 16 + 12);
            const float* hh = h2t + cin;           // h2t[k*65+cin]
            s += hh[0*65] * wv4a.x + hh[1*65] * wv4a.y + hh[2*65] * wv4a.z + hh[3*65] * wv4a.w;
            s += hh[4*65] * wv4b.x + hh[5*65] * wv4b.y + hh[6*65] * wv4b.z + hh[7*65] * wv4b.w;
            s += hh[8*65] * wv4c.x + hh[9*65] * wv4c.y + hh[10*65] * wv4c.z + hh[11*65] * wv4c.w;
            s += hh[12*65] * wv4d.x + hh[13*65] * wv4d.y + hh[14*65] * wv4d.z + hh[15*65] * wv4d.w;
        }
        prt[t] = s;   // cbuf dead (pool reads barriered above)
    }
    __syncthreads();
    if (t < 10) {
        float s = b3[t];
        #pragma unroll
        for (int l = 0; l < 16; ++l) s += prt[t * 16 + l];
        out[(size_t)n_img * 10 + t] = s;
    }
}

extern "C" void kernel_launch(void* const* d_in, const int* in_sizes, int n_in,
                              void* d_out, int out_size, void* d_ws, size_t ws_size,
                              hipStream_t stream) {
    const float* x  = (const float*)d_in[0];
    const float* w1 = (const float*)d_in[1];
    const float* b1 = (const float*)d_in[2];
    const float* w2 = (const float*)d_in[3];
    const float* b2 = (const float*)d_in[4];
    const float* w3 = (const float*)d_in[5];
    const float* b3 = (const float*)d_in[6];
    float* out = (float*)d_out;
    short* w2r = (short*)d_ws;            // 36864 bf16 = 73728 B

    const int B = in_sizes[0] / 784;      // 2048
    prep_w2<<<144, 256, 0, stream>>>(w2, w2r);
    convnet_fused<<<B, 256, 0, stream>>>(x, w1, b1, w2r, b2, w3, b3, out);
}